// Round 1
// baseline (646.207 us; speedup 1.0000x reference)
//
#include <hip/hip_runtime.h>
#include <hip/hip_bf16.h>
#include <cstdint>

#define CCH 48
#define DD 128
#define HH 128
#define WW 128
#define NVOX (DD*HH*WW)        // 2,097,152 voxels
#define NPTS 2097152

typedef unsigned int uint;
typedef unsigned short ushort_t;

__device__ __forceinline__ ushort_t f2bf_rne(float f) {
    uint u = __float_as_uint(f);
    uint r = (u + 0x7fffu + ((u >> 16) & 1u)) >> 16;
    return (ushort_t)r;
}

// Kernel 1: grid_t[v*48 + c] = bf16(k0[c*NVOX + v] + former[c*NVOX + v])
// Channel-major coalesced reads (1 thread = 1 voxel, loop c), channel-last packed stores.
__global__ __launch_bounds__(256) void fuse_transpose_kernel(
    const float* __restrict__ k0, const float* __restrict__ former,
    ushort_t* __restrict__ grid_t)
{
    const int v = blockIdx.x * 256 + threadIdx.x;
    float vals[CCH];
#pragma unroll
    for (int c = 0; c < CCH; ++c)
        vals[c] = k0[(size_t)c * NVOX + v] + former[(size_t)c * NVOX + v];

    uint4* dst = reinterpret_cast<uint4*>(grid_t + (size_t)v * CCH);
#pragma unroll
    for (int i = 0; i < 6; ++i) {
        uint4 u;
        u.x = (uint)f2bf_rne(vals[i*8+0]) | ((uint)f2bf_rne(vals[i*8+1]) << 16);
        u.y = (uint)f2bf_rne(vals[i*8+2]) | ((uint)f2bf_rne(vals[i*8+3]) << 16);
        u.z = (uint)f2bf_rne(vals[i*8+4]) | ((uint)f2bf_rne(vals[i*8+5]) << 16);
        u.w = (uint)f2bf_rne(vals[i*8+6]) | ((uint)f2bf_rne(vals[i*8+7]) << 16);
        dst[i] = u;
    }
}

// accumulate 24 channels (3 x uint4 = 24 bf16) with weight wgt
__device__ __forceinline__ void corner_acc(const ushort_t* __restrict__ base,
                                           float wgt, float acc[24])
{
    const uint4* p = reinterpret_cast<const uint4*>(base);
    uint4 a = p[0], b = p[1], c = p[2];
    uint us[12] = {a.x,a.y,a.z,a.w, b.x,b.y,b.z,b.w, c.x,c.y,c.z,c.w};
#pragma unroll
    for (int j = 0; j < 12; ++j) {
        acc[2*j]   = fmaf(wgt, __uint_as_float(us[j] << 16),        acc[2*j]);
        acc[2*j+1] = fmaf(wgt, __uint_as_float(us[j] & 0xffff0000u), acc[2*j+1]);
    }
}

// Kernel 2: 2 lanes per point, 24 channels per lane.
__global__ __launch_bounds__(256) void sample_kernel(
    const float* __restrict__ pts, const ushort_t* __restrict__ grid_t,
    float* __restrict__ out)
{
    const int tid = blockIdx.x * 256 + threadIdx.x;
    const int n   = tid >> 1;
    const int sub = tid & 1;

    const float px = pts[n*3+0], py = pts[n*3+1], pz = pts[n*3+2];
    const float ix = (px + 1.0f) * 63.5f;   // 0.5*(W-1)
    const float iy = (py + 1.0f) * 63.5f;
    const float iz = (pz + 1.0f) * 63.5f;
    const float xf = floorf(ix), yf = floorf(iy), zf = floorf(iz);
    const float wx = ix - xf, wy = iy - yf, wz = iz - zf;
    int x0 = (int)xf, y0 = (int)yf, z0 = (int)zf;
    int x1 = x0 + 1, y1 = y0 + 1, z1 = z0 + 1;
    x0 = min(max(x0,0), WW-1); x1 = min(max(x1,0), WW-1);
    y0 = min(max(y0,0), HH-1); y1 = min(max(y1,0), HH-1);
    z0 = min(max(z0,0), DD-1); z1 = min(max(z1,0), DD-1);

    const float wx0 = 1.0f - wx, wy0 = 1.0f - wy, wz0 = 1.0f - wz;

    float acc[24];
#pragma unroll
    for (int k = 0; k < 24; ++k) acc[k] = 0.0f;

    const int HWn = HH*WW;
    const int bz0 = z0*HWn, bz1 = z1*HWn;
    const int by0 = y0*WW,  by1 = y1*WW;
    const int so  = sub*24;

    corner_acc(grid_t + (size_t)(bz0+by0+x0)*CCH + so, wx0*wy0*wz0, acc);
    corner_acc(grid_t + (size_t)(bz0+by0+x1)*CCH + so, wx *wy0*wz0, acc);
    corner_acc(grid_t + (size_t)(bz0+by1+x0)*CCH + so, wx0*wy *wz0, acc);
    corner_acc(grid_t + (size_t)(bz0+by1+x1)*CCH + so, wx *wy *wz0, acc);
    corner_acc(grid_t + (size_t)(bz1+by0+x0)*CCH + so, wx0*wy0*wz , acc);
    corner_acc(grid_t + (size_t)(bz1+by0+x1)*CCH + so, wx *wy0*wz , acc);
    corner_acc(grid_t + (size_t)(bz1+by1+x0)*CCH + so, wx0*wy *wz , acc);
    corner_acc(grid_t + (size_t)(bz1+by1+x1)*CCH + so, wx *wy *wz , acc);

    float4* o = reinterpret_cast<float4*>(out + (size_t)n*CCH + so);
#pragma unroll
    for (int i = 0; i < 6; ++i)
        o[i] = make_float4(acc[i*4+0], acc[i*4+1], acc[i*4+2], acc[i*4+3]);
}

// Fallback (only if workspace too small): correct but slow direct gather in f32.
__global__ __launch_bounds__(256) void sample_naive(
    const float* __restrict__ pts, const float* __restrict__ k0,
    const float* __restrict__ former, float* __restrict__ out)
{
    const int n = blockIdx.x * 256 + threadIdx.x;
    if (n >= NPTS) return;
    const float px = pts[n*3+0], py = pts[n*3+1], pz = pts[n*3+2];
    const float ix = (px + 1.0f) * 63.5f;
    const float iy = (py + 1.0f) * 63.5f;
    const float iz = (pz + 1.0f) * 63.5f;
    const float xf = floorf(ix), yf = floorf(iy), zf = floorf(iz);
    const float wx = ix - xf, wy = iy - yf, wz = iz - zf;
    int x0 = (int)xf, y0 = (int)yf, z0 = (int)zf;
    int x1 = x0 + 1, y1 = y0 + 1, z1 = z0 + 1;
    x0 = min(max(x0,0), WW-1); x1 = min(max(x1,0), WW-1);
    y0 = min(max(y0,0), HH-1); y1 = min(max(y1,0), HH-1);
    z0 = min(max(z0,0), DD-1); z1 = min(max(z1,0), DD-1);
    const float wx0 = 1.0f - wx, wy0 = 1.0f - wy, wz0 = 1.0f - wz;
    const int HWn = HH*WW;
    const int v000 = z0*HWn + y0*WW + x0, v100 = z0*HWn + y0*WW + x1;
    const int v010 = z0*HWn + y1*WW + x0, v110 = z0*HWn + y1*WW + x1;
    const int v001 = z1*HWn + y0*WW + x0, v101 = z1*HWn + y0*WW + x1;
    const int v011 = z1*HWn + y1*WW + x0, v111 = z1*HWn + y1*WW + x1;
    const float w000 = wx0*wy0*wz0, w100 = wx*wy0*wz0;
    const float w010 = wx0*wy*wz0,  w110 = wx*wy*wz0;
    const float w001 = wx0*wy0*wz,  w101 = wx*wy0*wz;
    const float w011 = wx0*wy*wz,   w111 = wx*wy*wz;
    for (int c = 0; c < CCH; ++c) {
        const float* g0 = k0     + (size_t)c * NVOX;
        const float* g1 = former + (size_t)c * NVOX;
        float s = 0.0f;
        s += w000 * (g0[v000] + g1[v000]);
        s += w100 * (g0[v100] + g1[v100]);
        s += w010 * (g0[v010] + g1[v010]);
        s += w110 * (g0[v110] + g1[v110]);
        s += w001 * (g0[v001] + g1[v001]);
        s += w101 * (g0[v101] + g1[v101]);
        s += w011 * (g0[v011] + g1[v011]);
        s += w111 * (g0[v111] + g1[v111]);
        out[(size_t)n*CCH + c] = s;
    }
}

extern "C" void kernel_launch(void* const* d_in, const int* in_sizes, int n_in,
                              void* d_out, int out_size, void* d_ws, size_t ws_size,
                              hipStream_t stream) {
    const float* ray_pts = (const float*)d_in[0];
    const float* k0      = (const float*)d_in[1];
    const float* former  = (const float*)d_in[2];
    float* out = (float*)d_out;

    const size_t need = (size_t)NVOX * CCH * sizeof(ushort_t); // 201,326,592 B
    if (ws_size >= need) {
        ushort_t* grid_t = (ushort_t*)d_ws;
        fuse_transpose_kernel<<<NVOX/256, 256, 0, stream>>>(k0, former, grid_t);
        sample_kernel<<<(NPTS*2)/256, 256, 0, stream>>>(ray_pts, grid_t, out);
    } else {
        sample_naive<<<NPTS/256, 256, 0, stream>>>(ray_pts, k0, former, out);
    }
}